// Round 1
// baseline (763.591 us; speedup 1.0000x reference)
//
#include <hip/hip_runtime.h>
#include <hip/hip_bf16.h>

#define MODEL 2048
#define NHEAD 16
#define HDIM  128
#define BB    2
#define LL    2048
#define N1    (3*MODEL)      // 6144
#define MTOT  (BB*LL)        // 4096

typedef __hip_bfloat16 bf16;
typedef __attribute__((ext_vector_type(8))) short bf16x8;
typedef __attribute__((ext_vector_type(4))) float f32x4;

static __device__ __forceinline__ f32x4 mfma16(bf16x8 a, bf16x8 b, f32x4 c) {
  return __builtin_amdgcn_mfma_f32_16x16x32_bf16(a, b, c, 0, 0, 0);
}

// ---------------- prep: f32 -> bf16 (vectorized x4) ----------------
__global__ void k_cvt(const float* __restrict__ in, bf16* __restrict__ out, int n4) {
  int i = blockIdx.x * blockDim.x + threadIdx.x;
  if (i < n4) {
    float4 v = ((const float4*)in)[i];
    bf16* o = out + (size_t)i * 4;
    o[0] = __float2bfloat16(v.x);
    o[1] = __float2bfloat16(v.y);
    o[2] = __float2bfloat16(v.z);
    o[3] = __float2bfloat16(v.w);
  }
}

// ---------------- prep: transpose f32 [R][C] -> bf16 [C][R] ----------------
__global__ __launch_bounds__(256)
void k_transpose(const float* __restrict__ in, bf16* __restrict__ out, int R, int C) {
  __shared__ float t[32][33];
  const int c0 = blockIdx.x * 32, r0 = blockIdx.y * 32;
  const int tx = threadIdx.x & 31;
  const int ty = threadIdx.x >> 5;   // 0..7
#pragma unroll
  for (int i = 0; i < 4; ++i)
    t[ty + 8*i][tx] = in[(size_t)(r0 + ty + 8*i) * C + c0 + tx];
  __syncthreads();
#pragma unroll
  for (int i = 0; i < 4; ++i)
    out[(size_t)(c0 + ty + 8*i) * R + r0 + tx] = __float2bfloat16(t[tx][ty + 8*i]);
}

// ---------------- GEMM: C = A[M][K] * BT[N][K]^T, 128x128 tile ----------------
// EPI==1: RoPE + scatter into Q/K (row-major per head) and V^T (d-major per head)
// EPI==2: add bias, write f32
template<int EPI>
__global__ __launch_bounds__(256)
void k_gemm(const bf16* __restrict__ A, const bf16* __restrict__ BT,
            int M, int N, int K,
            float* __restrict__ Cout, const float* __restrict__ bias,
            bf16* __restrict__ Qb, bf16* __restrict__ Kb, bf16* __restrict__ VTb,
            const float* __restrict__ cosT, const float* __restrict__ sinT)
{
  __shared__ bf16 As[128][40];   // +8 pad, rows stay 16B-aligned (80 B stride)
  __shared__ bf16 Bs[128][40];

  const int tid  = threadIdx.x;
  const int wid  = tid >> 6, lane = tid & 63;
  const int wm   = wid >> 1, wn = wid & 1;
  const int lr   = lane & 15, lkg = lane >> 4;
  const int m0   = blockIdx.y * 128, n0 = blockIdx.x * 128;

  // staging assignment: 512 chunks of 16B; thread t does chunk t and t+256
  const int ra = tid >> 2;            // 0..63
  const int oa = (tid & 3) * 8;       // 0,8,16,24
  const bf16* Ap0 = A  + (size_t)(m0 + ra)      * K + oa;
  const bf16* Ap1 = A  + (size_t)(m0 + ra + 64) * K + oa;
  const bf16* Bp0 = BT + (size_t)(n0 + ra)      * K + oa;
  const bf16* Bp1 = BT + (size_t)(n0 + ra + 64) * K + oa;

  const f32x4 vzero = {0.f, 0.f, 0.f, 0.f};
  f32x4 acc[4][4];
#pragma unroll
  for (int i = 0; i < 4; ++i) {
#pragma unroll
    for (int j = 0; j < 4; ++j) acc[i][j] = vzero;
  }

  const int nk = K / 32;
  for (int kt = 0; kt < nk; ++kt) {
    bf16x8 a0 = *(const bf16x8*)(Ap0 + kt * 32);
    bf16x8 a1 = *(const bf16x8*)(Ap1 + kt * 32);
    bf16x8 b0 = *(const bf16x8*)(Bp0 + kt * 32);
    bf16x8 b1 = *(const bf16x8*)(Bp1 + kt * 32);
    __syncthreads();                       // previous iter's LDS reads done
    *(bf16x8*)&As[ra][oa]      = a0;
    *(bf16x8*)&As[ra + 64][oa] = a1;
    *(bf16x8*)&Bs[ra][oa]      = b0;
    *(bf16x8*)&Bs[ra + 64][oa] = b1;
    __syncthreads();
    bf16x8 af[4], bfr[4];
#pragma unroll
    for (int mb = 0; mb < 4; ++mb) af[mb]  = *(const bf16x8*)&As[wm*64 + mb*16 + lr][lkg*8];
#pragma unroll
    for (int nb = 0; nb < 4; ++nb) bfr[nb] = *(const bf16x8*)&Bs[wn*64 + nb*16 + lr][lkg*8];
#pragma unroll
    for (int mb = 0; mb < 4; ++mb) {
#pragma unroll
      for (int nb = 0; nb < 4; ++nb)
        acc[mb][nb] = mfma16(af[mb], bfr[nb], acc[mb][nb]);
    }
  }

  if constexpr (EPI == 1) {
    const float inv_sqrt_d = 0.08838834764831845f;  // 1/sqrt(128)
#pragma unroll
    for (int nb = 0; nb < 4; ++nb) {
      const int gcol_base = n0 + wn*64 + nb*16;     // multiple of 16; wave-uniform
      const int section = gcol_base >> 11;          // 0=q 1=k 2=v (uniform)
      const int cc = (gcol_base & 2047) + lr;       // col within section
      const int h = cc >> 7, d = cc & 127;
#pragma unroll
      for (int mb = 0; mb < 4; ++mb) {
#pragma unroll
        for (int reg = 0; reg < 4; ++reg) {
          const int grow = m0 + wm*64 + mb*16 + lkg*4 + reg;
          const int bidx = grow >> 11, lseq = grow & 2047;
          float val = acc[mb][nb][reg];
          if (section < 2) {
            // RoPE: pairs (2i,2i+1) are adjacent lanes (d parity == lane parity)
            float p = __shfl_xor(val, 1);
            const int fi = d >> 1;
            float cv = cosT[(size_t)lseq * 64 + fi];
            float sv = sinT[(size_t)lseq * 64 + fi];
            float r = (d & 1) ? fmaf(p, sv, val * cv)      // odd: te*sin + to*cos
                              : fmaf(val, cv, -p * sv);    // even: te*cos - to*sin
            if (section == 0) {
              r *= inv_sqrt_d;  // fold softmax scale into Q
              Qb[((size_t)(bidx*NHEAD + h) * LL + lseq) * HDIM + d] = __float2bfloat16(r);
            } else {
              Kb[((size_t)(bidx*NHEAD + h) * LL + lseq) * HDIM + d] = __float2bfloat16(r);
            }
          } else {
            VTb[((size_t)(bidx*NHEAD + h) * HDIM + d) * LL + lseq] = __float2bfloat16(val);
          }
        }
      }
    }
  } else {
#pragma unroll
    for (int nb = 0; nb < 4; ++nb) {
      const int gcol = n0 + wn*64 + nb*16 + lr;
      const float bv = bias[gcol];
#pragma unroll
      for (int mb = 0; mb < 4; ++mb) {
#pragma unroll
        for (int reg = 0; reg < 4; ++reg) {
          const int grow = m0 + wm*64 + mb*16 + lkg*4 + reg;
          Cout[(size_t)grow * N + gcol] = acc[mb][nb][reg] + bv;
        }
      }
    }
  }
}

// ---------------- flash attention: 4 waves/block, 16 q-rows per wave ----------------
__global__ __launch_bounds__(256)
void k_attn(const bf16* __restrict__ Qb, const bf16* __restrict__ Kb,
            const bf16* __restrict__ VTb, bf16* __restrict__ attnA)
{
  __shared__ bf16 Plds[4][16][40];   // per-wave private P tile (16 x 32, +8 pad)
  const int bh  = blockIdx.y;                       // b*16 + h
  const int qt  = (gridDim.x - 1) - blockIdx.x;     // heavy tiles first
  const int wid = threadIdx.x >> 6, lane = threadIdx.x & 63;
  const int lr  = lane & 15, lkg = lane >> 4;
  const int q0  = qt * 64 + wid * 16;

  const bf16* Qh = Qb  + (size_t)bh * LL * HDIM;
  const bf16* Kh = Kb  + (size_t)bh * LL * HDIM;
  const bf16* Vh = VTb + (size_t)bh * HDIM * LL;

  const f32x4 vzero = {0.f, 0.f, 0.f, 0.f};
  bf16x8 qf[4];
#pragma unroll
  for (int kk = 0; kk < 4; ++kk)
    qf[kk] = *(const bf16x8*)(Qh + (size_t)(q0 + lr) * HDIM + kk*32 + lkg*8);

  f32x4 oacc[8];
#pragma unroll
  for (int i = 0; i < 8; ++i) oacc[i] = vzero;
  float mrow[4] = {-INFINITY, -INFINITY, -INFINITY, -INFINITY};
  float lrow[4] = {0.f, 0.f, 0.f, 0.f};

  const int ktmax = (q0 + 15) >> 5;
  for (int kt = 0; kt <= ktmax; ++kt) {
    const int kbase = kt * 32;
    f32x4 s0 = vzero, s1 = vzero;
#pragma unroll
    for (int kk = 0; kk < 4; ++kk) {
      bf16x8 kf0 = *(const bf16x8*)(Kh + (size_t)(kbase + lr)      * HDIM + kk*32 + lkg*8);
      bf16x8 kf1 = *(const bf16x8*)(Kh + (size_t)(kbase + 16 + lr) * HDIM + kk*32 + lkg*8);
      s0 = mfma16(qf[kk], kf0, s0);
      s1 = mfma16(qf[kk], kf1, s1);
    }
    const int colA = kbase + lr, colB = colA + 16;
    float sc[4];
#pragma unroll
    for (int reg = 0; reg < 4; ++reg) {
      const int row = q0 + lkg*4 + reg;
      float a = (colA <= row) ? s0[reg] : -INFINITY;   // causal mask
      float b = (colB <= row) ? s1[reg] : -INFINITY;
      float tm = fmaxf(a, b);
      tm = fmaxf(tm, __shfl_xor(tm, 1));
      tm = fmaxf(tm, __shfl_xor(tm, 2));
      tm = fmaxf(tm, __shfl_xor(tm, 4));
      tm = fmaxf(tm, __shfl_xor(tm, 8));
      const float mnew  = fmaxf(mrow[reg], tm);
      const float scale = __expf(mrow[reg] - mnew);    // first iter: exp(-inf)=0
      mrow[reg] = mnew;
      const float p0 = __expf(a - mnew);
      const float p1 = __expf(b - mnew);
      float rs = p0 + p1;
      rs += __shfl_xor(rs, 1);
      rs += __shfl_xor(rs, 2);
      rs += __shfl_xor(rs, 4);
      rs += __shfl_xor(rs, 8);
      lrow[reg] = lrow[reg] * scale + rs;
      sc[reg] = scale;
      Plds[wid][lkg*4 + reg][lr]      = __float2bfloat16(p0);
      Plds[wid][lkg*4 + reg][lr + 16] = __float2bfloat16(p1);
    }
#pragma unroll
    for (int db = 0; db < 8; ++db) {
      oacc[db][0] *= sc[0]; oacc[db][1] *= sc[1];
      oacc[db][2] *= sc[2]; oacc[db][3] *= sc[3];
    }
    // wave-private LDS: ensure P writes land before A-frag read (no cross-wave sync)
    asm volatile("s_waitcnt lgkmcnt(0)" ::: "memory");
    bf16x8 pf = *(const bf16x8*)&Plds[wid][lr][lkg*8];
#pragma unroll
    for (int db = 0; db < 8; ++db) {
      bf16x8 vf = *(const bf16x8*)(Vh + (size_t)(db*16 + lr) * LL + kbase + lkg*8);
      oacc[db] = mfma16(pf, vf, oacc[db]);
    }
  }

  const int b = bh >> 4, h = bh & 15;
#pragma unroll
  for (int reg = 0; reg < 4; ++reg) {
    const float inv = 1.0f / lrow[reg];
    const int row = q0 + lkg*4 + reg;
    bf16* dst = attnA + ((size_t)(b*LL + row)) * MODEL + h * HDIM;
#pragma unroll
    for (int db = 0; db < 8; ++db)
      dst[db*16 + lr] = __float2bfloat16(oacc[db][reg] * inv);
  }
}

// ---------------- launch ----------------
extern "C" void kernel_launch(void* const* d_in, const int* in_sizes, int n_in,
                              void* d_out, int out_size, void* d_ws, size_t ws_size,
                              hipStream_t stream)
{
  const float* x    = (const float*)d_in[0];
  const float* cosT = (const float*)d_in[1];
  const float* sinT = (const float*)d_in[2];
  const float* Wqkv = (const float*)d_in[3];
  const float* Wc   = (const float*)d_in[4];
  const float* bc   = (const float*)d_in[5];
  float* out = (float*)d_out;

  // workspace layout (bytes):
  //   x16    @ 0         : 4096*2048*2  = 16,777,216   (reused as attnA later)
  //   WqkvT  @ 16777216  : 6144*2048*2  = 25,165,824
  //   WcT    @ 41943040  : 2048*2048*2  =  8,388,608
  //   Qb     @ 50331648  : 16,777,216
  //   Kb     @ 67108864  : 16,777,216
  //   VTb    @ 83886080  : 16,777,216   -> total 100,663,296 B
  if (ws_size < 100663296u) return;
  char* w = (char*)d_ws;
  bf16* x16   = (bf16*)(w);
  bf16* WqkvT = (bf16*)(w + (size_t)16777216);
  bf16* WcT   = (bf16*)(w + (size_t)41943040);
  bf16* Qb    = (bf16*)(w + (size_t)50331648);
  bf16* Kb    = (bf16*)(w + (size_t)67108864);
  bf16* VTb   = (bf16*)(w + (size_t)83886080);
  bf16* attnA = x16;   // overlay: x16 dead after GEMM1

  k_cvt<<<(MTOT*MODEL/4 + 255)/256, 256, 0, stream>>>(x, x16, MTOT*MODEL/4);
  k_transpose<<<dim3(N1/32,    MODEL/32), 256, 0, stream>>>(Wqkv, WqkvT, MODEL, N1);
  k_transpose<<<dim3(MODEL/32, MODEL/32), 256, 0, stream>>>(Wc,   WcT,   MODEL, MODEL);

  k_gemm<1><<<dim3(N1/128, MTOT/128), 256, 0, stream>>>(
      x16, WqkvT, MTOT, N1, MODEL,
      nullptr, nullptr, Qb, Kb, VTb, cosT, sinT);

  k_attn<<<dim3(LL/64, BB*NHEAD), 256, 0, stream>>>(Qb, Kb, VTb, attnA);

  k_gemm<2><<<dim3(MODEL/128, MTOT/128), 256, 0, stream>>>(
      attnA, WcT, MTOT, MODEL, MODEL,
      out, bc, nullptr, nullptr, nullptr, nullptr, nullptr);
}

// Round 2
// 403.897 us; speedup vs baseline: 1.8906x; 1.8906x over previous
//
#include <hip/hip_runtime.h>
#include <hip/hip_bf16.h>

#define MODEL 2048
#define NHEAD 16
#define HDIM  128
#define BB    2
#define LL    2048
#define N1    (3*MODEL)      // 6144
#define MTOT  (BB*LL)        // 4096

typedef __hip_bfloat16 bf16;
typedef __attribute__((ext_vector_type(8))) short bf16x8;
typedef __attribute__((ext_vector_type(4))) float f32x4;

static __device__ __forceinline__ f32x4 mfma16(bf16x8 a, bf16x8 b, f32x4 c) {
  return __builtin_amdgcn_mfma_f32_16x16x32_bf16(a, b, c, 0, 0, 0);
}

// async global->LDS DMA, 16B per lane; LDS base must be wave-uniform, dest linear
static __device__ __forceinline__ void gl_lds16(const void* g, void* l) {
  __builtin_amdgcn_global_load_lds(
      (const __attribute__((address_space(1))) unsigned int*)g,
      (__attribute__((address_space(3))) unsigned int*)l, 16, 0, 0);
}

// ---------------- prep: f32 -> bf16 (vectorized x4) ----------------
__global__ void k_cvt(const float* __restrict__ in, bf16* __restrict__ out, int n4) {
  int i = blockIdx.x * blockDim.x + threadIdx.x;
  if (i < n4) {
    float4 v = ((const float4*)in)[i];
    bf16* o = out + (size_t)i * 4;
    o[0] = __float2bfloat16(v.x);
    o[1] = __float2bfloat16(v.y);
    o[2] = __float2bfloat16(v.z);
    o[3] = __float2bfloat16(v.w);
  }
}

// ---------------- prep: transpose f32 [R][C] -> bf16 [C][R] ----------------
__global__ __launch_bounds__(256)
void k_transpose(const float* __restrict__ in, bf16* __restrict__ out, int R, int C) {
  __shared__ float t[32][33];
  const int c0 = blockIdx.x * 32, r0 = blockIdx.y * 32;
  const int tx = threadIdx.x & 31;
  const int ty = threadIdx.x >> 5;   // 0..7
#pragma unroll
  for (int i = 0; i < 4; ++i)
    t[ty + 8*i][tx] = in[(size_t)(r0 + ty + 8*i) * C + c0 + tx];
  __syncthreads();
#pragma unroll
  for (int i = 0; i < 4; ++i)
    out[(size_t)(c0 + ty + 8*i) * R + r0 + tx] = __float2bfloat16(t[tx][ty + 8*i]);
}

// ---------------- GEMM: C = A[M][K] * BT[N][K]^T, 128x128 tile, m97 structure ----------------
// EPI==1: RoPE + scatter into Q/K (row-major per head) and V^T (d-major per head)
// EPI==2: add bias, write f32
template<int EPI>
__global__ __launch_bounds__(256)
void k_gemm(const bf16* __restrict__ A, const bf16* __restrict__ BT,
            int M, int N, int K,
            float* __restrict__ Cout, const float* __restrict__ bias,
            bf16* __restrict__ Qb, bf16* __restrict__ Kb, bf16* __restrict__ VTb,
            const float* __restrict__ cosT, const float* __restrict__ sinT)
{
  __shared__ bf16 As[128][32];   // linear: required by global_load_lds
  __shared__ bf16 Bs[128][32];

  const int tid  = threadIdx.x;
  const int wid  = tid >> 6, lane = tid & 63;
  const int wm   = wid >> 1, wn = wid & 1;
  const int lr   = lane & 15, lkg = lane >> 4;
  const int m0   = blockIdx.y * 128, n0 = blockIdx.x * 128;

  // staging: wave wid owns rows [wid*32, wid*32+32); one gl_lds covers 16 rows
  const int sr = lane >> 2;           // 0..15 row within 16-row chunk
  const int so = (lane & 3) * 8;      // elem offset 0,8,16,24
  const bf16* Ag0 = A  + (size_t)(m0 + wid*32 + sr)      * K + so;
  const bf16* Ag1 = A  + (size_t)(m0 + wid*32 + 16 + sr) * K + so;
  const bf16* Bg0 = BT + (size_t)(n0 + wid*32 + sr)      * K + so;
  const bf16* Bg1 = BT + (size_t)(n0 + wid*32 + 16 + sr) * K + so;
  bf16* Al0 = &As[wid*32][0];         // wave-uniform LDS bases
  bf16* Al1 = &As[wid*32 + 16][0];
  bf16* Bl0 = &Bs[wid*32][0];
  bf16* Bl1 = &Bs[wid*32 + 16][0];

  const f32x4 vzero = {0.f, 0.f, 0.f, 0.f};
  f32x4 acc[4][4];
#pragma unroll
  for (int i = 0; i < 4; ++i)
#pragma unroll
    for (int j = 0; j < 4; ++j) acc[i][j] = vzero;

  const int nk = K / 32;
  for (int kt = 0; kt < nk; ++kt) {
    __syncthreads();                       // prev iter's LDS reads done
    gl_lds16(Ag0 + kt*32, Al0);
    gl_lds16(Ag1 + kt*32, Al1);
    gl_lds16(Bg0 + kt*32, Bl0);
    gl_lds16(Bg1 + kt*32, Bl1);
    __syncthreads();                       // vmcnt(0) drained by compiler here
    bf16x8 af[4], bfr[4];
#pragma unroll
    for (int mb = 0; mb < 4; ++mb) af[mb]  = *(const bf16x8*)&As[wm*64 + mb*16 + lr][lkg*8];
#pragma unroll
    for (int nb = 0; nb < 4; ++nb) bfr[nb] = *(const bf16x8*)&Bs[wn*64 + nb*16 + lr][lkg*8];
#pragma unroll
    for (int mb = 0; mb < 4; ++mb)
#pragma unroll
      for (int nb = 0; nb < 4; ++nb)
        acc[mb][nb] = mfma16(af[mb], bfr[nb], acc[mb][nb]);
  }

  if constexpr (EPI == 1) {
    const float inv_sqrt_d = 0.08838834764831845f;  // 1/sqrt(128)
#pragma unroll
    for (int nb = 0; nb < 4; ++nb) {
      const int gcol_base = n0 + wn*64 + nb*16;     // multiple of 16; wave-uniform
      const int section = gcol_base >> 11;          // 0=q 1=k 2=v (uniform)
      const int cc = (gcol_base & 2047) + lr;       // col within section
      const int h = cc >> 7, d = cc & 127;
#pragma unroll
      for (int mb = 0; mb < 4; ++mb) {
#pragma unroll
        for (int reg = 0; reg < 4; ++reg) {
          const int grow = m0 + wm*64 + mb*16 + lkg*4 + reg;
          const int bidx = grow >> 11, lseq = grow & 2047;
          float val = acc[mb][nb][reg];
          if (section < 2) {
            // RoPE: pairs (2i,2i+1) are adjacent lanes (d parity == lane parity)
            float p = __shfl_xor(val, 1);
            const int fi = d >> 1;
            float cv = cosT[(size_t)lseq * 64 + fi];
            float sv = sinT[(size_t)lseq * 64 + fi];
            float r = (d & 1) ? fmaf(p, sv, val * cv)      // odd: te*sin + to*cos
                              : fmaf(val, cv, -p * sv);    // even: te*cos - to*sin
            if (section == 0) {
              r *= inv_sqrt_d;  // fold softmax scale into Q
              Qb[((size_t)(bidx*NHEAD + h) * LL + lseq) * HDIM + d] = __float2bfloat16(r);
            } else {
              Kb[((size_t)(bidx*NHEAD + h) * LL + lseq) * HDIM + d] = __float2bfloat16(r);
            }
          } else {
            VTb[((size_t)(bidx*NHEAD + h) * HDIM + d) * LL + lseq] = __float2bfloat16(val);
          }
        }
      }
    }
  } else {
#pragma unroll
    for (int nb = 0; nb < 4; ++nb) {
      const int gcol = n0 + wn*64 + nb*16 + lr;
      const float bv = bias[gcol];
#pragma unroll
      for (int mb = 0; mb < 4; ++mb) {
#pragma unroll
        for (int reg = 0; reg < 4; ++reg) {
          const int grow = m0 + wm*64 + mb*16 + lkg*4 + reg;
          Cout[(size_t)grow * N + gcol] = acc[mb][nb][reg] + bv;
        }
      }
    }
  }
}

// ---------------- flash attention v2 ----------------
// 4 waves/block, 32 q-rows/wave (128/block); KV tiles of 64 staged in LDS,
// reg-prefetch of next tile overlaps compute (T14). 64 MFMAs/iter/wave.
__global__ __launch_bounds__(256, 2)
void k_attn(const bf16* __restrict__ Qb, const bf16* __restrict__ Kb,
            const bf16* __restrict__ VTb, bf16* __restrict__ attnA)
{
  __shared__ bf16 Ks[64][136];    // kv-row major, pad 8: stride 272B -> 2-way max
  __shared__ bf16 Vs[128][72];    // d-row major (V^T), pad 8: stride 144B
  __shared__ bf16 Ps[4][32][72];  // per-wave P tile (32 q x 64 kv)

  const int bh  = blockIdx.y;                       // b*16 + h
  const int qb  = (gridDim.x - 1) - blockIdx.x;     // heavy q-blocks first
  const int tid = threadIdx.x;
  const int wid = tid >> 6, lane = tid & 63;
  const int lr  = lane & 15, lkg = lane >> 4;
  const int Q0  = qb * 128;
  const int q0w = Q0 + wid * 32;

  const bf16* Qh = Qb  + (size_t)bh * LL * HDIM;
  const bf16* Kh = Kb  + (size_t)bh * LL * HDIM;
  const bf16* Vh = VTb + (size_t)bh * HDIM * LL;

  const f32x4 vzero = {0.f, 0.f, 0.f, 0.f};
  bf16x8 qf[2][4];
#pragma unroll
  for (int qr = 0; qr < 2; ++qr)
#pragma unroll
    for (int kk = 0; kk < 4; ++kk)
      qf[qr][kk] = *(const bf16x8*)(Qh + (size_t)(q0w + qr*16 + lr) * HDIM + kk*32 + lkg*8);

  f32x4 oacc[2][8];
#pragma unroll
  for (int qr = 0; qr < 2; ++qr)
#pragma unroll
    for (int db = 0; db < 8; ++db) oacc[qr][db] = vzero;
  float mrow[2][4], lrow[2][4];
#pragma unroll
  for (int qr = 0; qr < 2; ++qr)
#pragma unroll
    for (int r = 0; r < 4; ++r) { mrow[qr][r] = -INFINITY; lrow[qr][r] = 0.f; }

  const int NT = Q0 / 64 + 2;     // tiles of 64 kv cols covering [0, Q0+128)
  bf16x8 kpre[4], vpre[4];
  // prologue: prefetch tile 0
#pragma unroll
  for (int j = 0; j < 4; ++j) {
    const int c = j*256 + tid;
    kpre[j] = *(const bf16x8*)(Kh + (size_t)(c >> 4) * HDIM + (c & 15) * 8);
    vpre[j] = *(const bf16x8*)(Vh + (size_t)(c >> 3) * LL + (c & 7) * 8);
  }

  for (int kt = 0; kt < NT; ++kt) {
    const int kbase = kt * 64;
    __syncthreads();                    // all waves done reading LDS (prev tile)
#pragma unroll
    for (int j = 0; j < 4; ++j) {
      const int c = j*256 + tid;
      *(bf16x8*)&Ks[c >> 4][(c & 15) * 8] = kpre[j];
      *(bf16x8*)&Vs[c >> 3][(c & 7) * 8]  = vpre[j];
    }
    __syncthreads();                    // tile kt visible to all waves
    if (kt + 1 < NT) {                  // issue next-tile loads; hide under compute
#pragma unroll
      for (int j = 0; j < 4; ++j) {
        const int c = j*256 + tid;
        kpre[j] = *(const bf16x8*)(Kh + (size_t)((kt+1)*64 + (c >> 4)) * HDIM + (c & 15) * 8);
        vpre[j] = *(const bf16x8*)(Vh + (size_t)(c >> 3) * LL + (kt+1)*64 + (c & 7) * 8);
      }
    }
    if (kbase <= q0w + 31) {            // skip tiles fully above the diagonal
      // ---- S = Q K^T (32 q x 64 kv) ----
      f32x4 s[2][4];
#pragma unroll
      for (int qr = 0; qr < 2; ++qr)
#pragma unroll
        for (int c = 0; c < 4; ++c) s[qr][c] = vzero;
#pragma unroll
      for (int c = 0; c < 4; ++c) {
        bf16x8 kf[4];
#pragma unroll
        for (int kk = 0; kk < 4; ++kk)
          kf[kk] = *(const bf16x8*)&Ks[c*16 + lr][kk*32 + lkg*8];
#pragma unroll
        for (int qr = 0; qr < 2; ++qr)
#pragma unroll
          for (int kk = 0; kk < 4; ++kk)
            s[qr][c] = mfma16(qf[qr][kk], kf[kk], s[qr][c]);
      }
      // ---- online softmax ----
#pragma unroll
      for (int qr = 0; qr < 2; ++qr) {
        float scl4[4];
#pragma unroll
        for (int reg = 0; reg < 4; ++reg) {
          const int row = q0w + qr*16 + lkg*4 + reg;
          float v0 = (kbase      + lr <= row) ? s[qr][0][reg] : -INFINITY;
          float v1 = (kbase + 16 + lr <= row) ? s[qr][1][reg] : -INFINITY;
          float v2 = (kbase + 32 + lr <= row) ? s[qr][2][reg] : -INFINITY;
          float v3 = (kbase + 48 + lr <= row) ? s[qr][3][reg] : -INFINITY;
          float tm = fmaxf(fmaxf(v0, v1), fmaxf(v2, v3));
          tm = fmaxf(tm, __shfl_xor(tm, 1));
          tm = fmaxf(tm, __shfl_xor(tm, 2));
          tm = fmaxf(tm, __shfl_xor(tm, 4));
          tm = fmaxf(tm, __shfl_xor(tm, 8));
          const float mnew = fmaxf(mrow[qr][reg], tm);
          const float scl  = __expf(mrow[qr][reg] - mnew);   // first tile: exp(-inf)=0
          mrow[qr][reg] = mnew;
          float p0 = __expf(v0 - mnew);
          float p1 = __expf(v1 - mnew);
          float p2 = __expf(v2 - mnew);
          float p3 = __expf(v3 - mnew);
          float rs = (p0 + p1) + (p2 + p3);
          rs += __shfl_xor(rs, 1);
          rs += __shfl_xor(rs, 2);
          rs += __shfl_xor(rs, 4);
          rs += __shfl_xor(rs, 8);
          lrow[qr][reg] = lrow[qr][reg] * scl + rs;
          scl4[reg] = scl;
          const int prow = qr*16 + lkg*4 + reg;
          Ps[wid][prow][lr]      = __float2bfloat16(p0);
          Ps[wid][prow][16 + lr] = __float2bfloat16(p1);
          Ps[wid][prow][32 + lr] = __float2bfloat16(p2);
          Ps[wid][prow][48 + lr] = __float2bfloat16(p3);
        }
#pragma unroll
        for (int db = 0; db < 8; ++db) {
          oacc[qr][db][0] *= scl4[0]; oacc[qr][db][1] *= scl4[1];
          oacc[qr][db][2] *= scl4[2]; oacc[qr][db][3] *= scl4[3];
        }
      }
      // wave-private P write -> read
      asm volatile("s_waitcnt lgkmcnt(0)" ::: "memory");
      __builtin_amdgcn_sched_barrier(0);
      // ---- O += P V ----
      bf16x8 pf[2][2];
#pragma unroll
      for (int qr = 0; qr < 2; ++qr)
#pragma unroll
        for (int k2 = 0; k2 < 2; ++k2)
          pf[qr][k2] = *(const bf16x8*)&Ps[wid][qr*16 + lr][k2*32 + lkg*8];
#pragma unroll
      for (int db = 0; db < 8; ++db) {
        bf16x8 vf0 = *(const bf16x8*)&Vs[db*16 + lr][lkg*8];
        bf16x8 vf1 = *(const bf16x8*)&Vs[db*16 + lr][32 + lkg*8];
#pragma unroll
        for (int qr = 0; qr < 2; ++qr) {
          oacc[qr][db] = mfma16(pf[qr][0], vf0, oacc[qr][db]);
          oacc[qr][db] = mfma16(pf[qr][1], vf1, oacc[qr][db]);
        }
      }
    }
  }

  const int b = bh >> 4, h = bh & 15;
#pragma unroll
  for (int qr = 0; qr < 2; ++qr)
#pragma unroll
    for (int reg = 0; reg < 4; ++reg) {
      const float inv = 1.0f / lrow[qr][reg];
      const int row = q0w + qr*16 + lkg*4 + reg;
      bf16* dst = attnA + ((size_t)(b*LL + row)) * MODEL + h * HDIM;
#pragma unroll
      for (int db = 0; db < 8; ++db)
        dst[db*16 + lr] = __float2bfloat16(oacc[qr][db][reg] * inv);
    }
}

// ---------------- launch ----------------
extern "C" void kernel_launch(void* const* d_in, const int* in_sizes, int n_in,
                              void* d_out, int out_size, void* d_ws, size_t ws_size,
                              hipStream_t stream)
{
  const float* x    = (const float*)d_in[0];
  const float* cosT = (const float*)d_in[1];
  const float* sinT = (const float*)d_in[2];
  const float* Wqkv = (const float*)d_in[3];
  const float* Wc   = (const float*)d_in[4];
  const float* bc   = (const float*)d_in[5];
  float* out = (float*)d_out;

  // workspace layout (bytes):
  //   x16    @ 0         : 16,777,216   (reused as attnA later)
  //   WqkvT  @ 16777216  : 25,165,824
  //   WcT    @ 41943040  :  8,388,608
  //   Qb     @ 50331648  : 16,777,216
  //   Kb     @ 67108864  : 16,777,216
  //   VTb    @ 83886080  : 16,777,216   -> total 100,663,296 B
  if (ws_size < 100663296u) return;
  char* w = (char*)d_ws;
  bf16* x16   = (bf16*)(w);
  bf16* WqkvT = (bf16*)(w + (size_t)16777216);
  bf16* WcT   = (bf16*)(w + (size_t)41943040);
  bf16* Qb    = (bf16*)(w + (size_t)50331648);
  bf16* Kb    = (bf16*)(w + (size_t)67108864);
  bf16* VTb   = (bf16*)(w + (size_t)83886080);
  bf16* attnA = x16;   // overlay: x16 dead after GEMM1

  k_cvt<<<(MTOT*MODEL/4 + 255)/256, 256, 0, stream>>>(x, x16, MTOT*MODEL/4);
  k_transpose<<<dim3(N1/32,    MODEL/32), 256, 0, stream>>>(Wqkv, WqkvT, MODEL, N1);
  k_transpose<<<dim3(MODEL/32, MODEL/32), 256, 0, stream>>>(Wc,   WcT,   MODEL, MODEL);

  k_gemm<1><<<dim3(N1/128, MTOT/128), 256, 0, stream>>>(
      x16, WqkvT, MTOT, N1, MODEL,
      nullptr, nullptr, Qb, Kb, VTb, cosT, sinT);

  k_attn<<<dim3(LL/128, BB*NHEAD), 256, 0, stream>>>(Qb, Kb, VTb, attnA);

  k_gemm<2><<<dim3(MODEL/128, MTOT/128), 256, 0, stream>>>(
      attnA, WcT, MTOT, MODEL, MODEL,
      out, bc, nullptr, nullptr, nullptr, nullptr, nullptr);
}